// Round 7
// baseline (1977.773 us; speedup 1.0000x reference)
//
#include <hip/hip_runtime.h>
#include <hip/hip_bf16.h>
#include <stdint.h>

#define BB 64
#define SS 2048
#define TT 128
#define GRP 4              // renorm interval AND em prefetch group (4*10.8 << 88.7 e-folds)

typedef __bf16 bf16x8 __attribute__((ext_vector_type(8)));
typedef float  f32x4  __attribute__((ext_vector_type(4)));

// Raw workgroup barrier that does NOT drain vmcnt (LDS ordering only).
__device__ __forceinline__ void wg_barrier_lds() {
    asm volatile("" ::: "memory");
    __builtin_amdgcn_s_waitcnt(0xc07f);   // lgkmcnt(0), vmcnt/expcnt no-wait
    __builtin_amdgcn_s_barrier();
    asm volatile("" ::: "memory");
}

// ---- bool-layout detection: mask[0,0] is always true (len >= 1024) ----
__device__ __forceinline__ int detect_mode(const void* maskp) {
    uint32_t w0 = ((const uint32_t*)maskp)[0];
    if (w0 == 1u) return 0;
    if (w0 == 0x3F800000u) return 2;
    if (w0 == 0x3F803F80u) return 3;
    return 1;
}
__device__ __forceinline__ int mask_at(const void* maskp, int mode, size_t idx) {
    if (mode == 0) return ((const int*)maskp)[idx] != 0;
    if (mode == 1) return ((const unsigned char*)maskp)[idx] != 0;
    if (mode == 2) return ((const float*)maskp)[idx] != 0.f;
    return ((const unsigned short*)maskp)[idx] != 0;
}

// ---- MFMA forward scan + posterior, TWO time-interleaved batches per block ----
// The two batches give each wave two independent per-step dependence chains:
// batch B's LDS/VALU/MFMA issue fills batch A's latency stalls and vice versa.
__global__ __launch_bounds__(256, 1) void fwd_kernel(
    const float* __restrict__ em, const void* __restrict__ maskp,
    const int* __restrict__ tags, const void* __restrict__ forb,
    const float* __restrict__ trans,
    const float* __restrict__ startt, const float* __restrict__ endt,
    double* __restrict__ zout, double* __restrict__ postout)
{
    const int t = threadIdx.x;
    const int w = t >> 6;          // wave 0..3 (owns t_out rows 32w..32w+31)
    const int lane = t & 63;
    const int q = lane >> 4;       // quad 0..3
    const int c = lane & 15;       // MFMA n-column (replicated)
    const int blk = blockIdx.x;
    const int bA = 2 * blk, bB = 2 * blk + 1;

    __shared__ __bf16 uS[2][2][TT];            // [buffer][batch][tag] bf16
    __shared__ __align__(16) float wred[2][4]; // [batch][wave] renorm maxes
    __shared__ int    redi[4];
    __shared__ double redd[4];
    __shared__ int    redc[4];
    __shared__ float  Minit[2];

    const int mode = detect_mode(maskp);

    // ---- lengths: waves 0,1 -> batch A; waves 2,3 -> batch B ----
    {
        int half = t >> 7, tid = t & 127;
        size_t base = (size_t)(2 * blk + half) * SS;
        int cnt = 0;
        for (int s = tid; s < SS; s += 128) cnt += mask_at(maskp, mode, base + s);
        #pragma unroll
        for (int off = 32; off >= 1; off >>= 1) cnt += __shfl_xor(cnt, off);
        if (lane == 0) redi[w] = cnt;
    }
    __syncthreads();
    const int lenA = redi[0] + redi[1];
    const int lenB = redi[2] + redi[3];
    const int maxlen = max(lenA, lenB);

    // ---- E^T A-fragments (register-resident; layout verified in R6) ----
    bf16x8 afrag[2][4];
    #pragma unroll
    for (int ml = 0; ml < 2; ++ml) {
        int col = 32 * w + 16 * ml + c;
        #pragma unroll
        for (int kt = 0; kt < 4; ++kt) {
            #pragma unroll
            for (int jj = 0; jj < 8; ++jj) {
                size_t idx = (size_t)(32 * kt + 8 * q + jj) * TT + col;
                afrag[ml][kt][jj] = mask_at(forb, mode, idx) ? (__bf16)0.f
                                                             : (__bf16)__expf(trans[idx]);
            }
        }
    }

    // ---- init u0 for both batches (threads 0..31) ----
    if (t < 32) {
        int cb = t >> 4, li = t & 15;
        const float* em0 = em + (size_t)(2 * blk + cb) * SS * TT;
        float a[8]; float mx = -1e30f;
        #pragma unroll
        for (int jj = 0; jj < 8; ++jj) {
            int j = li * 8 + jj;
            a[jj] = startt[j] + em0[j];
            mx = fmaxf(mx, a[jj]);
        }
        mx = fmaxf(mx, __shfl_xor(mx, 1)); mx = fmaxf(mx, __shfl_xor(mx, 2));
        mx = fmaxf(mx, __shfl_xor(mx, 4)); mx = fmaxf(mx, __shfl_xor(mx, 8));
        union { __bf16 h[8]; uint4 v; } pk;
        #pragma unroll
        for (int jj = 0; jj < 8; ++jj) pk.h[jj] = (__bf16)__expf(a[jj] - mx);
        *(uint4*)&uS[0][cb][li * 8] = pk.v;
        if (li == 0) Minit[cb] = mx;
    }
    __syncthreads();

    double CdA = (double)Minit[0], CdB = (double)Minit[1];
    float pendA = 1.0f, pendB = 1.0f;

    const float* emA = em + (size_t)bA * SS * TT;
    const float* emB = em + (size_t)bB * SS * TT;
    const int tag0 = 32 * w + 4 * q;
    const int tag1 = tag0 + 16;

    int cur = 0;

    auto step = [&](float4 eA0, float4 eA1, float4 eB0, float4 eB1, bool ren, int s) {
        const __bf16* ua = &uS[cur][0][0];
        const __bf16* ub = &uS[cur][1][0];
        // B-fragments for both batches (broadcast reads, conflict-free)
        bf16x8 fa0 = *(const bf16x8*)(ua + 8 * q);
        bf16x8 fa1 = *(const bf16x8*)(ua + 32 + 8 * q);
        bf16x8 fa2 = *(const bf16x8*)(ua + 64 + 8 * q);
        bf16x8 fa3 = *(const bf16x8*)(ua + 96 + 8 * q);
        bf16x8 fb0 = *(const bf16x8*)(ub + 8 * q);
        bf16x8 fb1 = *(const bf16x8*)(ub + 32 + 8 * q);
        bf16x8 fb2 = *(const bf16x8*)(ub + 64 + 8 * q);
        bf16x8 fb3 = *(const bf16x8*)(ub + 96 + 8 * q);

        const bool actA = (s < lenA), actB = (s < lenB);
        uint2 oldA0, oldA1, oldB0, oldB1;
        if (!actA) { oldA0 = *(const uint2*)(ua + tag0); oldA1 = *(const uint2*)(ua + tag1); }
        if (!actB) { oldB0 = *(const uint2*)(ub + tag0); oldB1 = *(const uint2*)(ub + tag1); }

        // scale factors (off the MFMA chain; overlap LDS waits)
        float sA00 = __expf(eA0.x) * pendA, sA01 = __expf(eA0.y) * pendA;
        float sA02 = __expf(eA0.z) * pendA, sA03 = __expf(eA0.w) * pendA;
        float sA10 = __expf(eA1.x) * pendA, sA11 = __expf(eA1.y) * pendA;
        float sA12 = __expf(eA1.z) * pendA, sA13 = __expf(eA1.w) * pendA;
        float sB00 = __expf(eB0.x) * pendB, sB01 = __expf(eB0.y) * pendB;
        float sB02 = __expf(eB0.z) * pendB, sB03 = __expf(eB0.w) * pendB;
        float sB10 = __expf(eB1.x) * pendB, sB11 = __expf(eB1.y) * pendB;
        float sB12 = __expf(eB1.z) * pendB, sB13 = __expf(eB1.w) * pendB;

        // 8 independent 2-deep MFMA chains (4 per batch)
        f32x4 xA0 = {0,0,0,0}, yA0 = {0,0,0,0}, xA1 = {0,0,0,0}, yA1 = {0,0,0,0};
        f32x4 xB0 = {0,0,0,0}, yB0 = {0,0,0,0}, xB1 = {0,0,0,0}, yB1 = {0,0,0,0};
        xA0 = __builtin_amdgcn_mfma_f32_16x16x32_bf16(afrag[0][0], fa0, xA0, 0, 0, 0);
        xA1 = __builtin_amdgcn_mfma_f32_16x16x32_bf16(afrag[1][0], fa0, xA1, 0, 0, 0);
        xB0 = __builtin_amdgcn_mfma_f32_16x16x32_bf16(afrag[0][0], fb0, xB0, 0, 0, 0);
        xB1 = __builtin_amdgcn_mfma_f32_16x16x32_bf16(afrag[1][0], fb0, xB1, 0, 0, 0);
        yA0 = __builtin_amdgcn_mfma_f32_16x16x32_bf16(afrag[0][2], fa2, yA0, 0, 0, 0);
        yA1 = __builtin_amdgcn_mfma_f32_16x16x32_bf16(afrag[1][2], fa2, yA1, 0, 0, 0);
        yB0 = __builtin_amdgcn_mfma_f32_16x16x32_bf16(afrag[0][2], fb2, yB0, 0, 0, 0);
        yB1 = __builtin_amdgcn_mfma_f32_16x16x32_bf16(afrag[1][2], fb2, yB1, 0, 0, 0);
        xA0 = __builtin_amdgcn_mfma_f32_16x16x32_bf16(afrag[0][1], fa1, xA0, 0, 0, 0);
        xA1 = __builtin_amdgcn_mfma_f32_16x16x32_bf16(afrag[1][1], fa1, xA1, 0, 0, 0);
        xB0 = __builtin_amdgcn_mfma_f32_16x16x32_bf16(afrag[0][1], fb1, xB0, 0, 0, 0);
        xB1 = __builtin_amdgcn_mfma_f32_16x16x32_bf16(afrag[1][1], fb1, xB1, 0, 0, 0);
        yA0 = __builtin_amdgcn_mfma_f32_16x16x32_bf16(afrag[0][3], fa3, yA0, 0, 0, 0);
        yA1 = __builtin_amdgcn_mfma_f32_16x16x32_bf16(afrag[1][3], fa3, yA1, 0, 0, 0);
        yB0 = __builtin_amdgcn_mfma_f32_16x16x32_bf16(afrag[0][3], fb3, yB0, 0, 0, 0);
        yB1 = __builtin_amdgcn_mfma_f32_16x16x32_bf16(afrag[1][3], fb3, yB1, 0, 0, 0);

        float vA00 = (xA0[0] + yA0[0]) * sA00, vA01 = (xA0[1] + yA0[1]) * sA01;
        float vA02 = (xA0[2] + yA0[2]) * sA02, vA03 = (xA0[3] + yA0[3]) * sA03;
        float vA10 = (xA1[0] + yA1[0]) * sA10, vA11 = (xA1[1] + yA1[1]) * sA11;
        float vA12 = (xA1[2] + yA1[2]) * sA12, vA13 = (xA1[3] + yA1[3]) * sA13;
        float vB00 = (xB0[0] + yB0[0]) * sB00, vB01 = (xB0[1] + yB0[1]) * sB01;
        float vB02 = (xB0[2] + yB0[2]) * sB02, vB03 = (xB0[3] + yB0[3]) * sB03;
        float vB10 = (xB1[0] + yB1[0]) * sB10, vB11 = (xB1[1] + yB1[1]) * sB11;
        float vB12 = (xB1[2] + yB1[2]) * sB12, vB13 = (xB1[3] + yB1[3]) * sB13;

        // write new u (c==0 lanes; frozen batches copy forward)
        if (c == 0) {
            union { __bf16 h[4]; uint2 v; } pA0, pA1, pB0, pB1;
            pA0.h[0] = (__bf16)vA00; pA0.h[1] = (__bf16)vA01;
            pA0.h[2] = (__bf16)vA02; pA0.h[3] = (__bf16)vA03;
            pA1.h[0] = (__bf16)vA10; pA1.h[1] = (__bf16)vA11;
            pA1.h[2] = (__bf16)vA12; pA1.h[3] = (__bf16)vA13;
            pB0.h[0] = (__bf16)vB00; pB0.h[1] = (__bf16)vB01;
            pB0.h[2] = (__bf16)vB02; pB0.h[3] = (__bf16)vB03;
            pB1.h[0] = (__bf16)vB10; pB1.h[1] = (__bf16)vB11;
            pB1.h[2] = (__bf16)vB12; pB1.h[3] = (__bf16)vB13;
            if (!actA) { pA0.v = oldA0; pA1.v = oldA1; }
            if (!actB) { pB0.v = oldB0; pB1.v = oldB1; }
            __bf16* na = &uS[cur ^ 1][0][0];
            __bf16* nb = &uS[cur ^ 1][1][0];
            *(uint2*)(na + tag0) = pA0.v;
            *(uint2*)(na + tag1) = pA1.v;
            *(uint2*)(nb + tag0) = pB0.v;
            *(uint2*)(nb + tag1) = pB1.v;
        }
        if (ren) {
            float mA = fmaxf(fmaxf(fmaxf(vA00, vA01), fmaxf(vA02, vA03)),
                             fmaxf(fmaxf(vA10, vA11), fmaxf(vA12, vA13)));
            float mB = fmaxf(fmaxf(fmaxf(vB00, vB01), fmaxf(vB02, vB03)),
                             fmaxf(fmaxf(vB10, vB11), fmaxf(vB12, vB13)));
            mA = fmaxf(mA, __shfl_xor(mA, 16)); mA = fmaxf(mA, __shfl_xor(mA, 32));
            mB = fmaxf(mB, __shfl_xor(mB, 16)); mB = fmaxf(mB, __shfl_xor(mB, 32));
            if (lane == 0) { wred[0][w] = mA; wred[1][w] = mB; }
        }
        wg_barrier_lds();
        if (ren) {
            float4 wa = *(const float4*)wred[0];
            float4 wb = *(const float4*)wred[1];
            float MA = fmaxf(fmaxf(wa.x, wa.y), fmaxf(wa.z, wa.w));
            float MB = fmaxf(fmaxf(wb.x, wb.y), fmaxf(wb.z, wb.w));
            if (actA) { pendA = 1.0f / MA; CdA += (double)__logf(MA); }
            if (actB) { pendB = 1.0f / MB; CdB += (double)__logf(MB); }
        } else {
            if (actA) pendA = 1.0f;
            if (actB) pendB = 1.0f;
        }
        cur ^= 1;
    };

    // ---- main scan: groups of GRP steps, em prefetched one full group ahead ----
    int k = 1;
    float4 cA0[GRP], cA1[GRP], cB0[GRP], cB1[GRP];
    #pragma unroll
    for (int g = 0; g < GRP; ++g) {
        int kk = k + g; kk = kk < SS ? kk : SS - 1;
        cA0[g] = *(const float4*)(emA + (size_t)kk * TT + tag0);
        cA1[g] = *(const float4*)(emA + (size_t)kk * TT + tag1);
        cB0[g] = *(const float4*)(emB + (size_t)kk * TT + tag0);
        cB1[g] = *(const float4*)(emB + (size_t)kk * TT + tag1);
    }

    while (k + GRP <= maxlen) {
        float4 nA0[GRP], nA1[GRP], nB0[GRP], nB1[GRP];
        #pragma unroll
        for (int g = 0; g < GRP; ++g) {
            int kk = k + GRP + g; kk = kk < SS ? kk : SS - 1;
            nA0[g] = *(const float4*)(emA + (size_t)kk * TT + tag0);
            nA1[g] = *(const float4*)(emA + (size_t)kk * TT + tag1);
            nB0[g] = *(const float4*)(emB + (size_t)kk * TT + tag0);
            nB1[g] = *(const float4*)(emB + (size_t)kk * TT + tag1);
        }
        #pragma unroll
        for (int g = 0; g < GRP; ++g)
            step(cA0[g], cA1[g], cB0[g], cB1[g], g == GRP - 1, k + g);
        #pragma unroll
        for (int g = 0; g < GRP; ++g) {
            cA0[g] = nA0[g]; cA1[g] = nA1[g]; cB0[g] = nB0[g]; cB1[g] = nB1[g];
        }
        k += GRP;
    }

    while (k < maxlen) {
        float4 eA0 = *(const float4*)(emA + (size_t)k * TT + tag0);
        float4 eA1 = *(const float4*)(emA + (size_t)k * TT + tag1);
        float4 eB0 = *(const float4*)(emB + (size_t)k * TT + tag0);
        float4 eB1 = *(const float4*)(emB + (size_t)k * TT + tag1);
        step(eA0, eA1, eB0, eB1, true, k);
        ++k;
    }

    // ---- z for both batches ----
    __syncthreads();   // full drain once before epilogue
    {
        const __bf16* ua = &uS[cur][0][0];
        const __bf16* ub = &uS[cur][1][0];
        float rA = 0.f, rB = 0.f;
        #pragma unroll
        for (int rr = 0; rr < 4; ++rr) {
            float e0 = __expf(endt[tag0 + rr]), e1 = __expf(endt[tag1 + rr]);
            rA += (float)ua[tag0 + rr] * e0 + (float)ua[tag1 + rr] * e1;
            rB += (float)ub[tag0 + rr] * e0 + (float)ub[tag1 + rr] * e1;
        }
        rA += __shfl_xor(rA, 16); rA += __shfl_xor(rA, 32);
        rB += __shfl_xor(rB, 16); rB += __shfl_xor(rB, 32);
        if (lane == 0) { wred[0][w] = rA; wred[1][w] = rB; }
    }
    __syncthreads();
    if (t == 0) {
        float4 wa = *(const float4*)wred[0];
        float4 wb = *(const float4*)wred[1];
        float totA = (wa.x + wa.y) + (wa.z + wa.w);
        float totB = (wb.x + wb.y) + (wb.z + wb.w);
        zout[bA] = CdA + (double)__logf(pendA * totA);
        zout[bB] = CdB + (double)__logf(pendB * totB);
    }
    __syncthreads();

    // ---- posterior path scores: waves 0,1 -> batch A; waves 2,3 -> batch B ----
    {
        int half = t >> 7, tid = t & 127;
        int b = 2 * blk + half;
        int lenb = half ? lenB : lenA;
        const int* tg = tags + (size_t)b * SS;
        const float* emb = em + (size_t)b * SS * TT;
        double local = 0.0; int fcnt = 0;
        for (int kk = 1 + tid; kk < lenb; kk += 128) {
            int tp = tg[kk - 1], tc = tg[kk];
            if (mask_at(forb, mode, (size_t)tp * TT + tc)) fcnt++;
            else local += (double)trans[tp * TT + tc];
            local += (double)emb[(size_t)kk * TT + tc];
        }
        if (tid == 0) {
            local += (double)startt[tg[0]] + (double)emb[tg[0]];
            local += (double)endt[tg[lenb - 1]];
        }
        #pragma unroll
        for (int off = 32; off >= 1; off >>= 1) {
            local += __shfl_xor(local, off);
            fcnt  += __shfl_xor(fcnt, off);
        }
        if (lane == 0) { redd[w] = local; redc[w] = fcnt; }
        __syncthreads();
        if (t == 0)
            postout[bA] = (redd[0] + redd[1]) - 100000.0 * (double)(redc[0] + redc[1]);
        if (t == 1)
            postout[bB] = (redd[2] + redd[3]) - 100000.0 * (double)(redc[2] + redc[3]);
    }
}

// ---- nll = mean(post) - mean(z) ----
__global__ void fin_kernel(const double* __restrict__ z, const double* __restrict__ post,
                           float* __restrict__ out) {
    int t = threadIdx.x; // 64 threads, 1 wave
    double pv = post[t];
    double zv = z[t];
    #pragma unroll
    for (int off = 32; off >= 1; off >>= 1) {
        pv += __shfl_xor(pv, off);
        zv += __shfl_xor(zv, off);
    }
    if (t == 0) out[0] = (float)((pv - zv) / (double)BB);
}

extern "C" void kernel_launch(void* const* d_in, const int* in_sizes, int n_in,
                              void* d_out, int out_size, void* d_ws, size_t ws_size,
                              hipStream_t stream) {
    const float* em     = (const float*)d_in[0];
    const void*  maskp  = d_in[1];
    const int*   tags   = (const int*)d_in[2];
    const void*  forb   = d_in[3];
    const float* trans  = (const float*)d_in[4];
    const float* startt = (const float*)d_in[5];
    const float* endt   = (const float*)d_in[6];

    double* z    = (double*)d_ws;            // 64 doubles
    double* post = z + BB;                   // 64 doubles

    fwd_kernel<<<BB / 2, 256, 0, stream>>>(em, maskp, tags, forb, trans, startt, endt, z, post);
    fin_kernel<<<1, 64, 0, stream>>>(z, post, (float*)d_out);
}

// Round 8
// 1054.969 us; speedup vs baseline: 1.8747x; 1.8747x over previous
//
#include <hip/hip_runtime.h>
#include <hip/hip_bf16.h>
#include <stdint.h>

#define BB 64
#define SS 2048
#define TT 128
#define GRP 4              // em prefetch group depth

typedef int    i32x8 __attribute__((ext_vector_type(8)));
typedef float  f32x4 __attribute__((ext_vector_type(4)));

// Raw workgroup barrier that does NOT drain vmcnt (LDS ordering only).
__device__ __forceinline__ void wg_barrier_lds() {
    asm volatile("" ::: "memory");
    __builtin_amdgcn_s_waitcnt(0xc07f);   // lgkmcnt(0), vmcnt/expcnt no-wait
    __builtin_amdgcn_s_barrier();
    asm volatile("" ::: "memory");
}

// ---- bool-layout detection: mask[0,0] is always true (len >= 1024) ----
__device__ __forceinline__ int detect_mode(const void* maskp) {
    uint32_t w0 = ((const uint32_t*)maskp)[0];
    if (w0 == 1u) return 0;
    if (w0 == 0x3F800000u) return 2;
    if (w0 == 0x3F803F80u) return 3;
    return 1;
}
__device__ __forceinline__ int mask_at(const void* maskp, int mode, size_t idx) {
    if (mode == 0) return ((const int*)maskp)[idx] != 0;
    if (mode == 1) return ((const unsigned char*)maskp)[idx] != 0;
    if (mode == 2) return ((const float*)maskp)[idx] != 0.f;
    return ((const unsigned short*)maskp)[idx] != 0;
}

// ---- MX-fp8 K=128 forward scan + posterior, ONE batch per block (64 blocks) ----
// u' = (E^T u) * exp(em): one mfma_scale_f32_16x16x128 covers the FULL K=128
// per 16 output rows -> 2 MFMA per wave per step (vs 8 bf16 K=32 in R6).
// u stored fp8 e4m3 in LDS, renormalized every step to [128,256) by a
// power-of-2 scale; the exponent sum Rsum is tracked exactly as an int.
__global__ __launch_bounds__(256, 1) void fwd_kernel(
    const float* __restrict__ em, const void* __restrict__ maskp,
    const int* __restrict__ tags, const void* __restrict__ forb,
    const float* __restrict__ trans,
    const float* __restrict__ startt, const float* __restrict__ endt,
    double* __restrict__ zout, double* __restrict__ postout)
{
    const int t = threadIdx.x;
    const int w = t >> 6;          // wave 0..3 (owns u rows 32w..32w+31)
    const int lane = t & 63;
    const int q = lane >> 4;       // quad 0..3 (k-block / D row group)
    const int c = lane & 15;       // MFMA m/n column (n replicated)
    const int b = blockIdx.x;      // the batch

    __shared__ __align__(16) int   u8i[2][32];   // double-buffered u, fp8 (128 B each)
    __shared__ __align__(16) float wmaxS[4];     // per-wave max exchange
    __shared__ int    redi[4];
    __shared__ double redd[4];
    __shared__ int    redc[4];

    const int mode = detect_mode(maskp);

    // ---- length of this batch (contiguous mask prefix) ----
    {
        int cnt = 0;
        for (int s = t; s < SS; s += 256) cnt += mask_at(maskp, mode, (size_t)b * SS + s);
        #pragma unroll
        for (int off = 32; off >= 1; off >>= 1) cnt += __shfl_xor(cnt, off);
        if (lane == 0) redi[w] = cnt;
    }
    __syncthreads();
    const int len = redi[0] + redi[1] + redi[2] + redi[3];

    // ---- E^T A-fragments in fp8 (register-resident, 8 VGPR per M-tile) ----
    // A[m=c][k=32q+4d+jj] of tile (2w+ml): E[32q+4d+jj][32w+16ml+c]
    i32x8 afrag[2];
    #pragma unroll
    for (int ml = 0; ml < 2; ++ml) {
        int col = 32 * w + 16 * ml + c;
        #pragma unroll
        for (int d = 0; d < 8; ++d) {
            float x[4];
            #pragma unroll
            for (int jj = 0; jj < 4; ++jj) {
                size_t idx = (size_t)(32 * q + 4 * d + jj) * TT + col;
                x[jj] = mask_at(forb, mode, idx) ? 0.f : __expf(trans[idx]);
            }
            int dw = __builtin_amdgcn_cvt_pk_fp8_f32(x[0], x[1], 0, false);
            dw = __builtin_amdgcn_cvt_pk_fp8_f32(x[2], x[3], dw, true);
            afrag[ml][d] = dw;
        }
    }

    const float* emB = em + (size_t)b * SS * TT;
    const int tag0 = 32 * w + 4 * q;   // this lane's D rows (ml=0)
    const int tag1 = tag0 + 16;        // (ml=1)

    int Rsum = 0;
    int cur = 0;

    // ---- init: v = exp(start + em0) for this lane's 8 rows; pack to u8[0] ----
    {
        float4 s0 = *(const float4*)(startt + tag0);
        float4 s1 = *(const float4*)(startt + tag1);
        float4 e0 = *(const float4*)(emB + tag0);
        float4 e1 = *(const float4*)(emB + tag1);
        float v0 = __expf(s0.x + e0.x), v1 = __expf(s0.y + e0.y);
        float v2 = __expf(s0.z + e0.z), v3 = __expf(s0.w + e0.w);
        float v4 = __expf(s1.x + e1.x), v5 = __expf(s1.y + e1.y);
        float v6 = __expf(s1.z + e1.z), v7 = __expf(s1.w + e1.w);
        float pm = fmaxf(fmaxf(fmaxf(v0, v1), fmaxf(v2, v3)),
                         fmaxf(fmaxf(v4, v5), fmaxf(v6, v7)));
        pm = fmaxf(pm, __shfl_xor(pm, 16));
        pm = fmaxf(pm, __shfl_xor(pm, 32));
        if (lane == 0) wmaxS[w] = pm;
        __syncthreads();
        float4 wm = *(const float4*)wmaxS;
        float M = fmaxf(fmaxf(wm.x, wm.y), fmaxf(wm.z, wm.w));
        int mg = (int)((__float_as_uint(M) >> 23) & 0xff);
        Rsum += mg - 134;
        float pk = __uint_as_float((unsigned)(261 - mg) << 23);  // 2^(134-mg)
        int d0 = __builtin_amdgcn_cvt_pk_fp8_f32(v0 * pk, v1 * pk, 0, false);
        d0 = __builtin_amdgcn_cvt_pk_fp8_f32(v2 * pk, v3 * pk, d0, true);
        int d1 = __builtin_amdgcn_cvt_pk_fp8_f32(v4 * pk, v5 * pk, 0, false);
        d1 = __builtin_amdgcn_cvt_pk_fp8_f32(v6 * pk, v7 * pk, d1, true);
        if (c == 0) {
            u8i[0][8 * w + q] = d0;
            u8i[0][8 * w + q + 4] = d1;
        }
    }

    // ---- one scan step: em float4 pair already in registers ----
    auto step = [&](float4 e0, float4 e1) {
        wg_barrier_lds();                              // u8[cur] visible
        const int4* ub = (const int4*)&u8i[cur][0];
        int4 b0 = ub[2 * q];
        int4 b1 = ub[2 * q + 1];
        float x0 = __expf(e0.x), x1 = __expf(e0.y), x2 = __expf(e0.z), x3 = __expf(e0.w);
        float x4 = __expf(e1.x), x5 = __expf(e1.y), x6 = __expf(e1.z), x7 = __expf(e1.w);
        i32x8 bb;
        bb[0] = b0.x; bb[1] = b0.y; bb[2] = b0.z; bb[3] = b0.w;
        bb[4] = b1.x; bb[5] = b1.y; bb[6] = b1.z; bb[7] = b1.w;
        f32x4 zz = {0.f, 0.f, 0.f, 0.f};
        f32x4 a0 = __builtin_amdgcn_mfma_scale_f32_16x16x128_f8f6f4(
            afrag[0], bb, zz, 0, 0, 0, 127, 0, 127);
        f32x4 a1 = __builtin_amdgcn_mfma_scale_f32_16x16x128_f8f6f4(
            afrag[1], bb, zz, 0, 0, 0, 127, 0, 127);
        float v0 = a0[0] * x0, v1 = a0[1] * x1, v2 = a0[2] * x2, v3 = a0[3] * x3;
        float v4 = a1[0] * x4, v5 = a1[1] * x5, v6 = a1[2] * x6, v7 = a1[3] * x7;
        float pm = fmaxf(fmaxf(fmaxf(v0, v1), fmaxf(v2, v3)),
                         fmaxf(fmaxf(v4, v5), fmaxf(v6, v7)));
        pm = fmaxf(pm, __shfl_xor(pm, 16));
        pm = fmaxf(pm, __shfl_xor(pm, 32));
        if (lane == 0) wmaxS[w] = pm;
        wg_barrier_lds();                              // wmax visible
        float4 wm = *(const float4*)wmaxS;
        float M = fmaxf(fmaxf(wm.x, wm.y), fmaxf(wm.z, wm.w));
        int mg = (int)((__float_as_uint(M) >> 23) & 0xff);
        Rsum += mg - 134;
        float pk = __uint_as_float((unsigned)(261 - mg) << 23);  // 2^(134-mg)
        int d0 = __builtin_amdgcn_cvt_pk_fp8_f32(v0 * pk, v1 * pk, 0, false);
        d0 = __builtin_amdgcn_cvt_pk_fp8_f32(v2 * pk, v3 * pk, d0, true);
        int d1 = __builtin_amdgcn_cvt_pk_fp8_f32(v4 * pk, v5 * pk, 0, false);
        d1 = __builtin_amdgcn_cvt_pk_fp8_f32(v6 * pk, v7 * pk, d1, true);
        if (c == 0) {
            int* un = &u8i[cur ^ 1][0];
            un[8 * w + q] = d0;
            un[8 * w + q + 4] = d1;
        }
        cur ^= 1;
    };

    // ---- main scan: groups of GRP steps, em prefetched one full group ahead ----
    int k = 1;
    float4 emc0[GRP], emc1[GRP];
    #pragma unroll
    for (int g = 0; g < GRP; ++g) {
        int kk = k + g; kk = kk < SS ? kk : SS - 1;
        emc0[g] = *(const float4*)(emB + (size_t)kk * TT + tag0);
        emc1[g] = *(const float4*)(emB + (size_t)kk * TT + tag1);
    }

    while (k + GRP <= len) {
        float4 emn0[GRP], emn1[GRP];
        #pragma unroll
        for (int g = 0; g < GRP; ++g) {
            int kk = k + GRP + g; kk = kk < SS ? kk : SS - 1;
            emn0[g] = *(const float4*)(emB + (size_t)kk * TT + tag0);
            emn1[g] = *(const float4*)(emB + (size_t)kk * TT + tag1);
        }
        #pragma unroll
        for (int g = 0; g < GRP; ++g)
            step(emc0[g], emc1[g]);
        #pragma unroll
        for (int g = 0; g < GRP; ++g) { emc0[g] = emn0[g]; emc1[g] = emn1[g]; }
        k += GRP;
    }
    while (k < len) {
        float4 e0 = *(const float4*)(emB + (size_t)k * TT + tag0);
        float4 e1 = *(const float4*)(emB + (size_t)k * TT + tag1);
        step(e0, e1);
        ++k;
    }

    // ---- z = log(sum_j stored_j * exp(end_j)) + Rsum*ln2 ----
    __syncthreads();   // full drain; u8[cur] final visible
    if (t < 16) {
        const int* uf = &u8i[cur][0];
        int dA = uf[2 * t], dB = uf[2 * t + 1];
        const float* ep = endt + 8 * t;
        float s = 0.f;
        s += __builtin_amdgcn_cvt_f32_fp8(dA, 0) * __expf(ep[0]);
        s += __builtin_amdgcn_cvt_f32_fp8(dA, 1) * __expf(ep[1]);
        s += __builtin_amdgcn_cvt_f32_fp8(dA, 2) * __expf(ep[2]);
        s += __builtin_amdgcn_cvt_f32_fp8(dA, 3) * __expf(ep[3]);
        s += __builtin_amdgcn_cvt_f32_fp8(dB, 0) * __expf(ep[4]);
        s += __builtin_amdgcn_cvt_f32_fp8(dB, 1) * __expf(ep[5]);
        s += __builtin_amdgcn_cvt_f32_fp8(dB, 2) * __expf(ep[6]);
        s += __builtin_amdgcn_cvt_f32_fp8(dB, 3) * __expf(ep[7]);
        s += __shfl_xor(s, 1); s += __shfl_xor(s, 2);
        s += __shfl_xor(s, 4); s += __shfl_xor(s, 8);
        if (t == 0)
            zout[b] = (double)__logf(s) + (double)Rsum * 0.6931471805599453;
    }
    __syncthreads();

    // ---- posterior path score for this batch (256 threads strided) ----
    {
        const int* tg = tags + (size_t)b * SS;
        double local = 0.0; int fcnt = 0;
        for (int kk = 1 + t; kk < len; kk += 256) {
            int tp = tg[kk - 1], tc = tg[kk];
            if (mask_at(forb, mode, (size_t)tp * TT + tc)) fcnt++;
            else local += (double)trans[tp * TT + tc];
            local += (double)emB[(size_t)kk * TT + tc];
        }
        if (t == 0) {
            local += (double)startt[tg[0]] + (double)emB[tg[0]];
            local += (double)endt[tg[len - 1]];
        }
        #pragma unroll
        for (int off = 32; off >= 1; off >>= 1) {
            local += __shfl_xor(local, off);
            fcnt  += __shfl_xor(fcnt, off);
        }
        if (lane == 0) { redd[w] = local; redc[w] = fcnt; }
        __syncthreads();
        if (t == 0) {
            double tot = redd[0] + redd[1] + redd[2] + redd[3];
            int fc = redc[0] + redc[1] + redc[2] + redc[3];
            postout[b] = tot - 100000.0 * (double)fc;
        }
    }
}

// ---- nll = mean(post) - mean(z) ----
__global__ void fin_kernel(const double* __restrict__ z, const double* __restrict__ post,
                           float* __restrict__ out) {
    int t = threadIdx.x; // 64 threads, 1 wave
    double pv = post[t];
    double zv = z[t];
    #pragma unroll
    for (int off = 32; off >= 1; off >>= 1) {
        pv += __shfl_xor(pv, off);
        zv += __shfl_xor(zv, off);
    }
    if (t == 0) out[0] = (float)((pv - zv) / (double)BB);
}

extern "C" void kernel_launch(void* const* d_in, const int* in_sizes, int n_in,
                              void* d_out, int out_size, void* d_ws, size_t ws_size,
                              hipStream_t stream) {
    const float* em     = (const float*)d_in[0];
    const void*  maskp  = d_in[1];
    const int*   tags   = (const int*)d_in[2];
    const void*  forb   = d_in[3];
    const float* trans  = (const float*)d_in[4];
    const float* startt = (const float*)d_in[5];
    const float* endt   = (const float*)d_in[6];

    double* z    = (double*)d_ws;            // 64 doubles
    double* post = z + BB;                   // 64 doubles

    fwd_kernel<<<BB, 256, 0, stream>>>(em, maskp, tags, forb, trans, startt, endt, z, post);
    fin_kernel<<<1, 64, 0, stream>>>(z, post, (float*)d_out);
}